// Round 11
// baseline (922.974 us; speedup 1.0000x reference)
//
#include <hip/hip_runtime.h>

#define NN   100000
#define EE   1600000
#define HIDF 128
#define OUTF 64
#define KSEL 32
#define BSH  3                   // log2(nodes per bucket)
#define NBK  (NN >> BSH)         // 12500 buckets (100000 = 12500*8 exact)
#define CAPSH 8                  // log2(records per bucket capacity)
#define CAP  (1 << CAPSH)        // 256; Poisson(128) max over 12500 buckets ~ 177
#define GT   ((NN + 31) / 32)    // 3125 row tiles (32-row: maxk/relu)
#define GT64 ((NN + 63) / 64)    // 1563 row tiles (64-row: out64)
#define GE   ((EE + 255) / 256)  // 6250 edge blocks

static __device__ __forceinline__ unsigned int sortable_key(float f) {
    unsigned int u = __float_as_uint(f);
    return (u & 0x80000000u) ? ~u : (u | 0x80000000u);
}

// ================= fused K1: edge binning (atomic-bound) + input GEMM (VALU-bound) =================
// R8: interleave verified (+48us). Pattern of 3 blocks = [bin, bin, gemm].
__global__ __launch_bounds__(256, 2) void fused_bin_relu(const int* __restrict__ src,
                                                         const int* __restrict__ dst,
                                                         int* __restrict__ bcnt,
                                                         int* __restrict__ scnt,
                                                         int* __restrict__ bin,
                                                         const float* __restrict__ X,
                                                         const float* __restrict__ W,
                                                         const float* __restrict__ bias,
                                                         float* __restrict__ out) {
    __shared__ float As[32][128];   // 16KB (gemm branch only)
    __shared__ float Ws[16][128];   // 8KB
    const int tid = threadIdx.x;
    const int g = blockIdx.x / 3;
    const int r = blockIdx.x % 3;

    if (r < 2) {
        // ---- bin branch (edge block g*2+r) ----
        int i = (g * 2 + r) * 256 + tid;
        if (i < EE) {
            int s = src[i];
            int d = dst[i];
            int b = d >> BSH;
            int pos = atomicAdd(&bcnt[b], 1);
            if (pos < CAP) bin[(b << CAPSH) + pos] = (s << BSH) | (d & ((1 << BSH) - 1));
            atomicAdd(&scnt[s], 1);
        }
        return;
    }

    // ---- gemm_relu branch (R3-verified pattern, 32-row tile) ----
    const int rbase = g * 32;
    const int cc = tid & 31;
    const int r0 = (tid >> 5) * 4;
    const int n = NN;
    float acc[4][4];
#pragma unroll
    for (int i = 0; i < 4; ++i) { acc[i][0] = 0.f; acc[i][1] = 0.f; acc[i][2] = 0.f; acc[i][3] = 0.f; }

    float4 wreg0 = *(const float4*)(W + (size_t)tid * 4);
    float4 wreg1 = *(const float4*)(W + (size_t)(tid + 256) * 4);

    // stage A (row-guarded: x is not padded)
#pragma unroll
    for (int q = 0; q < 4; ++q) {
        int f = q * 256 + tid;
        int row = rbase + (f >> 5);
        float4 v = make_float4(0.f, 0.f, 0.f, 0.f);
        if (row < n) v = *(const float4*)(X + (size_t)row * 128 + (f & 31) * 4);
        *(float4*)&As[f >> 5][(f & 31) * 4] = v;
    }

    for (int p = 0; p < 8; ++p) {
        const int kb = p * 16;
        if (p) __syncthreads();
        *(float4*)&Ws[tid >> 5][(tid & 31) * 4] = wreg0;
        *(float4*)&Ws[(tid >> 5) + 8][(tid & 31) * 4] = wreg1;
        if (p < 7) {
            const float* wp = W + (size_t)(kb + 16) * 128;
            wreg0 = *(const float4*)(wp + (size_t)tid * 4);
            wreg1 = *(const float4*)(wp + (size_t)(tid + 256) * 4);
        }
        __syncthreads();
#pragma unroll
        for (int kq = 0; kq < 4; ++kq) {
            int k = kq * 4;
            float4 w0 = *(float4*)&Ws[k + 0][cc * 4];
            float4 w1 = *(float4*)&Ws[k + 1][cc * 4];
            float4 w2 = *(float4*)&Ws[k + 2][cc * 4];
            float4 w3 = *(float4*)&Ws[k + 3][cc * 4];
#pragma unroll
            for (int i = 0; i < 4; ++i) {
                float4 a = *(float4*)&As[r0 + i][kb + k];
                acc[i][0] += a.x * w0.x + a.y * w1.x + a.z * w2.x + a.w * w3.x;
                acc[i][1] += a.x * w0.y + a.y * w1.y + a.z * w2.y + a.w * w3.y;
                acc[i][2] += a.x * w0.z + a.y * w1.z + a.z * w2.z + a.w * w3.z;
                acc[i][3] += a.x * w0.w + a.y * w1.w + a.z * w2.w + a.w * w3.w;
            }
        }
    }
    float4 b4 = *(const float4*)(bias + cc * 4);
#pragma unroll
    for (int i = 0; i < 4; ++i) {
        int gr = rbase + r0 + i;
        if (gr < n) {
            float4 o = make_float4(fmaxf(acc[i][0] + b4.x, 0.f), fmaxf(acc[i][1] + b4.y, 0.f),
                                   fmaxf(acc[i][2] + b4.z, 0.f), fmaxf(acc[i][3] + b4.w, 0.f));
            *(float4*)(out + (size_t)gr * 128 + cc * 4) = o;
        }
    }
}

// ================= gemm+maxk COMPUTE (As pre-filled by caller; verified body) =================
static __device__ __forceinline__ void gemm_maxk_compute(float (*As)[128], float (*Ws)[128],
                                                         float4 wreg0, float4 wreg1,
                                                         const float* __restrict__ W,
                                                         const float* __restrict__ bias,
                                                         const int* __restrict__ scnt,
                                                         float* __restrict__ svals,
                                                         int n, int rbase) {
    const int tid = threadIdx.x;
    const int cc = tid & 31;
    const int r0 = (tid >> 5) * 4;
    float acc[4][4];
#pragma unroll
    for (int i = 0; i < 4; ++i) { acc[i][0] = 0.f; acc[i][1] = 0.f; acc[i][2] = 0.f; acc[i][3] = 0.f; }

    for (int p = 0; p < 8; ++p) {
        const int kb = p * 16;
        if (p) __syncthreads();
        *(float4*)&Ws[tid >> 5][(tid & 31) * 4] = wreg0;
        *(float4*)&Ws[(tid >> 5) + 8][(tid & 31) * 4] = wreg1;
        if (p < 7) {
            const float* wp = W + (size_t)(kb + 16) * 128;
            wreg0 = *(const float4*)(wp + (size_t)tid * 4);
            wreg1 = *(const float4*)(wp + (size_t)(tid + 256) * 4);
        }
        __syncthreads();
#pragma unroll
        for (int kq = 0; kq < 4; ++kq) {
            int k = kq * 4;
            float4 w0 = *(float4*)&Ws[k + 0][cc * 4];
            float4 w1 = *(float4*)&Ws[k + 1][cc * 4];
            float4 w2 = *(float4*)&Ws[k + 2][cc * 4];
            float4 w3 = *(float4*)&Ws[k + 3][cc * 4];
#pragma unroll
            for (int i = 0; i < 4; ++i) {
                float4 a = *(float4*)&As[r0 + i][kb + k];
                acc[i][0] += a.x * w0.x + a.y * w1.x + a.z * w2.x + a.w * w3.x;
                acc[i][1] += a.x * w0.y + a.y * w1.y + a.z * w2.y + a.w * w3.y;
                acc[i][2] += a.x * w0.z + a.y * w1.z + a.z * w2.z + a.w * w3.z;
                acc[i][3] += a.x * w0.w + a.y * w1.w + a.z * w2.w + a.w * w3.w;
            }
        }
    }

    // ---- fused MaxK select (verified logic; 4 rows/thread) ----
    const int lane = tid & 63;
    const int wvi = tid >> 6;
    const bool up = lane >= 32;
    const unsigned lt32 = (1u << (lane & 31)) - 1u;
    float4 b4 = *(const float4*)(bias + cc * 4);

    unsigned keys[4][4];
#pragma unroll
    for (int i = 0; i < 4; ++i) {
        acc[i][0] += b4.x; acc[i][1] += b4.y; acc[i][2] += b4.z; acc[i][3] += b4.w;
        keys[i][0] = sortable_key(acc[i][0]);
        keys[i][1] = sortable_key(acc[i][1]);
        keys[i][2] = sortable_key(acc[i][2]);
        keys[i][3] = sortable_key(acc[i][3]);
    }
    unsigned prefL[4], prefU[4];
#pragma unroll
    for (int i = 0; i < 4; ++i) { prefL[i] = 0u; prefU[i] = 0u; }

    for (int bit = 31; bit >= 8; --bit) {
        unsigned msk = 1u << bit;
#pragma unroll
        for (int i = 0; i < 4; ++i) {
            unsigned cL = prefL[i] | msk;
            unsigned cU = prefU[i] | msk;
            unsigned myc = up ? cU : cL;
            unsigned long long b0 = __ballot(keys[i][0] >= myc);
            unsigned long long b1 = __ballot(keys[i][1] >= myc);
            unsigned long long b2 = __ballot(keys[i][2] >= myc);
            unsigned long long b3 = __ballot(keys[i][3] >= myc);
            int cntL = __popc((unsigned)b0) + __popc((unsigned)b1) +
                       __popc((unsigned)b2) + __popc((unsigned)b3);
            int cntU = __popc((unsigned)(b0 >> 32)) + __popc((unsigned)(b1 >> 32)) +
                       __popc((unsigned)(b2 >> 32)) + __popc((unsigned)(b3 >> 32));
            prefL[i] = (cntL >= KSEL) ? cL : prefL[i];
            prefU[i] = (cntU >= KSEL) ? cU : prefU[i];
        }
    }

#pragma unroll 1
    for (int i = 0; i < 4; ++i) {
        int row = rbase + 8 * wvi + i + (up ? 4 : 0);
        unsigned myp = up ? prefU[i] : prefL[i];
        unsigned kb0 = keys[i][0] & 0xFFFFFF00u, kb1 = keys[i][1] & 0xFFFFFF00u;
        unsigned kb2 = keys[i][2] & 0xFFFFFF00u, kb3 = keys[i][3] & 0xFFFFFF00u;
        unsigned long long g0 = __ballot(kb0 > myp), g1 = __ballot(kb1 > myp);
        unsigned long long g2 = __ballot(kb2 > myp), g3 = __ballot(kb3 > myp);
        unsigned long long e0 = __ballot(kb0 == myp), e1 = __ballot(kb1 == myp);
        unsigned long long e2 = __ballot(kb2 == myp), e3 = __ballot(kb3 == myp);
        unsigned gh0 = up ? (unsigned)(g0 >> 32) : (unsigned)g0;
        unsigned gh1 = up ? (unsigned)(g1 >> 32) : (unsigned)g1;
        unsigned gh2 = up ? (unsigned)(g2 >> 32) : (unsigned)g2;
        unsigned gh3 = up ? (unsigned)(g3 >> 32) : (unsigned)g3;
        unsigned eh0 = up ? (unsigned)(e0 >> 32) : (unsigned)e0;
        unsigned eh1 = up ? (unsigned)(e1 >> 32) : (unsigned)e1;
        unsigned eh2 = up ? (unsigned)(e2 >> 32) : (unsigned)e2;
        unsigned eh3 = up ? (unsigned)(e3 >> 32) : (unsigned)e3;
        int m = __popc(gh0) + __popc(gh1) + __popc(gh2) + __popc(gh3);
        int need = KSEL - m;
        int gpos = __popc(gh0 & lt32) + __popc(gh1 & lt32) + __popc(gh2 & lt32) + __popc(gh3 & lt32);
        int epos = __popc(eh0 & lt32) + __popc(eh1 & lt32) + __popc(eh2 & lt32) + __popc(eh3 & lt32);
        bool ok = row < n;
        float ds = 0.f;
        if (ok) ds = rsqrtf((float)max(scnt[row], 1));
        size_t base = (size_t)row * 32;
        unsigned cbit = (unsigned)(lane & 31);
        // j = 0
        {
            int slot = -1;
            if (kb0 > myp) slot = gpos;
            else if (kb0 == myp && epos < need) slot = m + epos;
            if (slot >= 0 && ok) {
                unsigned u = (__float_as_uint(acc[i][0] * ds) & 0xFFFFFF80u) | (unsigned)(cc * 4 + 0);
                svals[base + slot] = __uint_as_float(u);
            }
            gpos += (gh0 >> cbit) & 1u;
            epos += (eh0 >> cbit) & 1u;
        }
        // j = 1
        {
            int slot = -1;
            if (kb1 > myp) slot = gpos;
            else if (kb1 == myp && epos < need) slot = m + epos;
            if (slot >= 0 && ok) {
                unsigned u = (__float_as_uint(acc[i][1] * ds) & 0xFFFFFF80u) | (unsigned)(cc * 4 + 1);
                svals[base + slot] = __uint_as_float(u);
            }
            gpos += (gh1 >> cbit) & 1u;
            epos += (eh1 >> cbit) & 1u;
        }
        // j = 2
        {
            int slot = -1;
            if (kb2 > myp) slot = gpos;
            else if (kb2 == myp && epos < need) slot = m + epos;
            if (slot >= 0 && ok) {
                unsigned u = (__float_as_uint(acc[i][2] * ds) & 0xFFFFFF80u) | (unsigned)(cc * 4 + 2);
                svals[base + slot] = __uint_as_float(u);
            }
            gpos += (gh2 >> cbit) & 1u;
            epos += (eh2 >> cbit) & 1u;
        }
        // j = 3
        {
            int slot = -1;
            if (kb3 > myp) slot = gpos;
            else if (kb3 == myp && epos < need) slot = m + epos;
            if (slot >= 0 && ok) {
                unsigned u = (__float_as_uint(acc[i][3] * ds) & 0xFFFFFF80u) | (unsigned)(cc * 4 + 3);
                svals[base + slot] = __uint_as_float(u);
            }
        }
    }
}

// ================= fused K2: gemm_maxk#1 (stages As from hbuf) + csr build =================
__global__ __launch_bounds__(256, 2) void fused_csr_maxk(const int* __restrict__ bin,
                                                         const int* __restrict__ bcnt,
                                                         int* __restrict__ row_off,
                                                         int* __restrict__ cnt_in,
                                                         float* __restrict__ dvin,
                                                         int* __restrict__ csr,
                                                         const float* __restrict__ A,
                                                         const float* __restrict__ W,
                                                         const float* __restrict__ bias,
                                                         const int* __restrict__ scnt,
                                                         float* __restrict__ svals) {
    __shared__ float As[32][128];
    __shared__ float Ws[16][128];
    const int tid = threadIdx.x;

    if (blockIdx.x >= GT) {
        // ---- csr branch: per-bucket node counts, offsets, scatter ----
        int* cnt8 = (int*)&As[0][0];
        int* cur8 = cnt8 + (1 << BSH);
        const int b = blockIdx.x - GT;
        if (tid < (1 << BSH)) cnt8[tid] = 0;
        __syncthreads();
        const int m = min(bcnt[b], CAP);
        const int base = b << CAPSH;
        for (int e = tid; e < m; e += 256) {
            atomicAdd(&cnt8[bin[base + e] & ((1 << BSH) - 1)], 1);
        }
        __syncthreads();
        if (tid < (1 << BSH)) {
            int pre = 0;
#pragma unroll
            for (int q = 0; q < (1 << BSH); ++q) pre += (q < tid) ? cnt8[q] : 0;
            int node = (b << BSH) + tid;
            int start = base + pre;
            if (node < NN) {
                row_off[node] = start;
                cnt_in[node] = cnt8[tid];
                dvin[node] = rsqrtf((float)max(cnt8[tid], 1));
            }
            cur8[tid] = start;
        }
        __syncthreads();
        for (int e = tid; e < m; e += 256) {
            int r = bin[base + e];
            int pos = atomicAdd(&cur8[r & ((1 << BSH) - 1)], 1);
            csr[pos] = r >> BSH;
        }
        return;
    }

    const int rbase = blockIdx.x * 32;
    float4 wreg0 = *(const float4*)(W + (size_t)tid * 4);
    float4 wreg1 = *(const float4*)(W + (size_t)(tid + 256) * 4);
#pragma unroll
    for (int q = 0; q < 4; ++q) {
        int f = q * 256 + tid;
        *(float4*)&As[f >> 5][(f & 31) * 4] =
            *(const float4*)(A + (size_t)rbase * 128 + (size_t)f * 4);   // hbuf padded
    }
    gemm_maxk_compute(As, Ws, wreg0, wreg1, W, bias, scnt, svals, NN, rbase);
}

// ================= fused K3: agg (layer1) -> As in LDS -> gemm_maxk (layer2) =================
// R10 budget: agg1(~65, latency-bound gather) + maxk2(~90, VALU) ran serialized.
// Fused per-tile: this block aggregates its 32 nodes into As directly (no hbuf
// round-trip, ~100MB saved), then runs the verified GEMM. Blocks in agg phase
// overlap blocks in GEMM phase on the same CU. svalsA (read) != svalsB (write).
__global__ __launch_bounds__(256, 2) void fused_agg_maxk(const float* __restrict__ svalsA,
                                                         const int* __restrict__ row_off,
                                                         const int* __restrict__ cnt_in,
                                                         const int* __restrict__ csr_src,
                                                         const float* __restrict__ dvin,
                                                         const float* __restrict__ bg,
                                                         const float* __restrict__ W,
                                                         const float* __restrict__ bias,
                                                         const int* __restrict__ scnt,
                                                         float* __restrict__ svalsB) {
    __shared__ float As[32][128];    // 16KB
    __shared__ float Ws[16][128];    // 8KB
    __shared__ float sc[4][2][128];  // 4KB wave-private agg scratch
    const int tid = threadIdx.x;
    const int wv = tid >> 6;
    const int lane = tid & 63;
    const int sub = lane >> 5;
    const int j = lane & 31;
    const int rbase = blockIdx.x * 32;   // 100000 = 3125*32 exact

    float4 wreg0 = *(const float4*)(W + (size_t)tid * 4);      // prefetch hides under agg
    float4 wreg1 = *(const float4*)(W + (size_t)(tid + 256) * 4);

    // ---- agg phase: each wave aggregates 8 nodes into As rows ----
    for (int u = 0; u < 8; ++u) {
        int node = rbase + wv * 8 + u;
        float* Ac = &sc[wv][sub][0];
        Ac[j] = 0.f; Ac[j + 32] = 0.f; Ac[j + 64] = 0.f; Ac[j + 96] = 0.f;
        int s0 = row_off[node], s1 = s0 + cnt_in[node];
        int e = s0 + sub;
        for (; e + 2 < s1; e += 4) {
            int sA = csr_src[e];
            int sB = csr_src[e + 2];
            float vA = svalsA[(size_t)sA * 32 + j];
            float vB = svalsA[(size_t)sB * 32 + j];
            Ac[(int)(__float_as_uint(vA) & 127u)] += vA;
            Ac[(int)(__float_as_uint(vB) & 127u)] += vB;
        }
        for (; e < s1; e += 2) {
            int sA = csr_src[e];
            float vA = svalsA[(size_t)sA * 32 + j];
            Ac[(int)(__float_as_uint(vA) & 127u)] += vA;
        }
        float dv = dvin[node];
        int rr = wv * 8 + u;
        As[rr][lane]      = (sc[wv][0][lane]      + sc[wv][1][lane])      * dv + bg[lane];
        As[rr][lane + 64] = (sc[wv][0][lane + 64] + sc[wv][1][lane + 64]) * dv + bg[lane + 64];
    }
    __syncthreads();

    gemm_maxk_compute(As, Ws, wreg0, wreg1, W, bias, scnt, svalsB, NN, rbase);
}

// ================= fused K4: agg (layer2) -> As in LDS -> out64 GEMM =================
// out64 GEMM body is the R3-verified 64-row version (R9 lesson: do not retile).
__global__ __launch_bounds__(256, 2) void fused_agg_out(const float* __restrict__ svalsB,
                                                        const int* __restrict__ row_off,
                                                        const int* __restrict__ cnt_in,
                                                        const int* __restrict__ csr_src,
                                                        const float* __restrict__ dvin,
                                                        const float* __restrict__ bg,
                                                        const float* __restrict__ W,
                                                        const float* __restrict__ bias,
                                                        float* __restrict__ out, int n) {
    __shared__ float As[64][128];    // 32KB
    __shared__ float Ws[32][64];     // 8KB
    __shared__ float sc[4][2][128];  // 4KB
    const int tid = threadIdx.x;
    const int wv = tid >> 6;
    const int lane = tid & 63;
    const int sub = lane >> 5;
    const int j = lane & 31;
    const int rbase = blockIdx.x * 64;

    float4 wreg0 = *(const float4*)(W + (size_t)tid * 4);
    float4 wreg1 = *(const float4*)(W + (size_t)(tid + 256) * 4);

    // ---- agg phase: each wave aggregates 16 nodes (node guard: last tile) ----
    for (int u = 0; u < 16; ++u) {
        int node = rbase + wv * 16 + u;
        float* Ac = &sc[wv][sub][0];
        Ac[j] = 0.f; Ac[j + 32] = 0.f; Ac[j + 64] = 0.f; Ac[j + 96] = 0.f;
        float dv = 0.f;
        if (node < n) {
            dv = dvin[node];
            int s0 = row_off[node], s1 = s0 + cnt_in[node];
            int e = s0 + sub;
            for (; e + 2 < s1; e += 4) {
                int sA = csr_src[e];
                int sB = csr_src[e + 2];
                float vA = svalsB[(size_t)sA * 32 + j];
                float vB = svalsB[(size_t)sB * 32 + j];
                Ac[(int)(__float_as_uint(vA) & 127u)] += vA;
                Ac[(int)(__float_as_uint(vB) & 127u)] += vB;
            }
            for (; e < s1; e += 2) {
                int sA = csr_src[e];
                float vA = svalsB[(size_t)sA * 32 + j];
                Ac[(int)(__float_as_uint(vA) & 127u)] += vA;
            }
        }
        int rr = wv * 16 + u;
        As[rr][lane]      = (sc[wv][0][lane]      + sc[wv][1][lane])      * dv + bg[lane];
        As[rr][lane + 64] = (sc[wv][0][lane + 64] + sc[wv][1][lane + 64]) * dv + bg[lane + 64];
    }
    __syncthreads();

    // ---- out64 GEMM compute (verified R3 body; As pre-filled) ----
    const int cc = tid & 15;
    const int r0 = (tid >> 4) * 4;
    float acc[4][4];
#pragma unroll
    for (int i = 0; i < 4; ++i) { acc[i][0] = 0.f; acc[i][1] = 0.f; acc[i][2] = 0.f; acc[i][3] = 0.f; }

    for (int p = 0; p < 4; ++p) {
        const int kb = p * 32;
        if (p) __syncthreads();
        *(float4*)&Ws[tid >> 4][(tid & 15) * 4] = wreg0;
        *(float4*)&Ws[(tid >> 4) + 16][(tid & 15) * 4] = wreg1;
        if (p < 3) {
            const float* wp = W + (size_t)(kb + 32) * 64;
            wreg0 = *(const float4*)(wp + (size_t)tid * 4);
            wreg1 = *(const float4*)(wp + (size_t)(tid + 256) * 4);
        }
        __syncthreads();
#pragma unroll
        for (int kq = 0; kq < 8; ++kq) {
            int k = kq * 4;
            float4 w0 = *(float4*)&Ws[k + 0][cc * 4];
            float4 w1 = *(float4*)&Ws[k + 1][cc * 4];
            float4 w2 = *(float4*)&Ws[k + 2][cc * 4];
            float4 w3 = *(float4*)&Ws[k + 3][cc * 4];
#pragma unroll
            for (int i = 0; i < 4; ++i) {
                float4 a = *(float4*)&As[r0 + i][kb + k];
                acc[i][0] += a.x * w0.x + a.y * w1.x + a.z * w2.x + a.w * w3.x;
                acc[i][1] += a.x * w0.y + a.y * w1.y + a.z * w2.y + a.w * w3.y;
                acc[i][2] += a.x * w0.z + a.y * w1.z + a.z * w2.z + a.w * w3.z;
                acc[i][3] += a.x * w0.w + a.y * w1.w + a.z * w2.w + a.w * w3.w;
            }
        }
    }
    float4 b4 = *(const float4*)(bias + cc * 4);
#pragma unroll
    for (int i = 0; i < 4; ++i) {
        int gr = rbase + r0 + i;
        if (gr < n) {
            float4 o = make_float4(acc[i][0] + b4.x, acc[i][1] + b4.y,
                                   acc[i][2] + b4.z, acc[i][3] + b4.w);
            *(float4*)(out + (size_t)gr * 64 + cc * 4) = o;
        }
    }
}

extern "C" void kernel_launch(void* const* d_in, const int* in_sizes, int n_in,
                              void* d_out, int out_size, void* d_ws, size_t ws_size,
                              hipStream_t stream) {
    const float* x     = (const float*)d_in[0];
    const int*   src   = (const int*)d_in[1];
    const int*   dst   = (const int*)d_in[2];
    const float* W_in  = (const float*)d_in[3];
    const float* b_in  = (const float*)d_in[4];
    const float* W1    = (const float*)d_in[5];
    const float* b1    = (const float*)d_in[6];
    const float* bg1   = (const float*)d_in[7];
    const float* W2    = (const float*)d_in[8];
    const float* b2    = (const float*)d_in[9];
    const float* bg2   = (const float*)d_in[10];
    const float* W_out = (const float*)d_in[11];
    const float* b_out = (const float*)d_in[12];
    float* out = (float*)d_out;

    char* p = (char*)d_ws;
    auto carve = [&](size_t bytes) {
        char* r = p;
        p += (bytes + 255) & ~(size_t)255;
        return r;
    };
    int*   scnt    = (int*)carve((size_t)NN * 4);
    int*   bcnt    = (int*)carve((size_t)NBK * 4);
    float* dvin    = (float*)carve((size_t)NN * 4);
    int*   row_off = (int*)carve((size_t)NN * 4);
    int*   cnt_in  = (int*)carve((size_t)NN * 4);
    int*   bin     = (int*)carve((size_t)NBK * CAP * 4);     // 12.8MB packed records
    int*   csr_src = (int*)carve((size_t)NBK * CAP * 4);     // 12.8MB fixed-stride
    float* hbuf    = (float*)carve((size_t)(NN + 128) * HIDF * 4);  // padded rows
    float* svalsA  = (float*)carve((size_t)NN * KSEL * 4);   // layer-1 maxk output
    float* svalsB  = (float*)carve((size_t)NN * KSEL * 4);   // layer-2 maxk output

    hipMemsetAsync(scnt, 0, (size_t)NN * 4, stream);
    hipMemsetAsync(bcnt, 0, (size_t)NBK * 4, stream);

    // K1: binning interleaved 2:1 with input GEMM (pattern of 3: bin,bin,gemm)
    fused_bin_relu<<<GT * 3, 256, 0, stream>>>(src, dst, bcnt, scnt, bin,
                                               x, W_in, b_in, hbuf);
    // K2: layer-1 GEMM+MaxK overlapped with CSR materialization -> svalsA
    fused_csr_maxk<<<GT + NBK, 256, 0, stream>>>(bin, bcnt, row_off, cnt_in, dvin, csr_src,
                                                 hbuf, W1, b1, scnt, svalsA);
    // K3: agg(layer1) fused with layer-2 GEMM+MaxK -> svalsB
    fused_agg_maxk<<<GT, 256, 0, stream>>>(svalsA, row_off, cnt_in, csr_src, dvin, bg1,
                                           W2, b2, scnt, svalsB);
    // K4: agg(layer2) fused with output GEMM -> out
    fused_agg_out<<<GT64, 256, 0, stream>>>(svalsB, row_off, cnt_in, csr_src, dvin, bg2,
                                            W_out, b_out, out, NN);
}

// Round 12
// 596.946 us; speedup vs baseline: 1.5462x; 1.5462x over previous
//
#include <hip/hip_runtime.h>

#define NN   100000
#define EE   1600000
#define HIDF 128
#define OUTF 64
#define KSEL 32
#define BSH  3                   // log2(nodes per bucket)
#define NBK  (NN >> BSH)         // 12500 buckets (100000 = 12500*8 exact)
#define CAPSH 8                  // log2(records per bucket capacity)
#define CAP  (1 << CAPSH)        // 256; Poisson(128) max over 12500 buckets ~ 177
#define GT   ((NN + 31) / 32)    // 3125 row tiles (32-row: maxk/relu)
#define GT64 ((NN + 63) / 64)    // 1563 row tiles (64-row: out64)
#define GE   ((EE + 255) / 256)  // 6250 edge blocks

static __device__ __forceinline__ unsigned int sortable_key(float f) {
    unsigned int u = __float_as_uint(f);
    return (u & 0x80000000u) ? ~u : (u | 0x80000000u);
}

// ================= fused K1: edge binning (atomic-bound) + input GEMM (VALU-bound) =================
// R8: interleave verified (+48us). Pattern of 3 blocks = [bin, bin, gemm].
// R11 lesson: this fusion works because the bin branch needs ~no resources;
// do NOT fuse latency-bound gather phases into resource-heavy kernels.
__global__ __launch_bounds__(256, 2) void fused_bin_relu(const int* __restrict__ src,
                                                         const int* __restrict__ dst,
                                                         int* __restrict__ bcnt,
                                                         int* __restrict__ scnt,
                                                         int* __restrict__ bin,
                                                         const float* __restrict__ X,
                                                         const float* __restrict__ W,
                                                         const float* __restrict__ bias,
                                                         float* __restrict__ out) {
    __shared__ float As[32][128];   // 16KB (gemm branch only)
    __shared__ float Ws[16][128];   // 8KB
    const int tid = threadIdx.x;
    const int g = blockIdx.x / 3;
    const int r = blockIdx.x % 3;

    if (r < 2) {
        // ---- bin branch (edge block g*2+r) ----
        int i = (g * 2 + r) * 256 + tid;
        if (i < EE) {
            int s = src[i];
            int d = dst[i];
            int b = d >> BSH;
            int pos = atomicAdd(&bcnt[b], 1);
            if (pos < CAP) bin[(b << CAPSH) + pos] = (s << BSH) | (d & ((1 << BSH) - 1));
            atomicAdd(&scnt[s], 1);
        }
        return;
    }

    // ---- gemm_relu branch (R3-verified pattern, 32-row tile) ----
    const int rbase = g * 32;
    const int cc = tid & 31;
    const int r0 = (tid >> 5) * 4;
    const int n = NN;
    float acc[4][4];
#pragma unroll
    for (int i = 0; i < 4; ++i) { acc[i][0] = 0.f; acc[i][1] = 0.f; acc[i][2] = 0.f; acc[i][3] = 0.f; }

    float4 wreg0 = *(const float4*)(W + (size_t)tid * 4);
    float4 wreg1 = *(const float4*)(W + (size_t)(tid + 256) * 4);

    // stage A (row-guarded: x is not padded)
#pragma unroll
    for (int q = 0; q < 4; ++q) {
        int f = q * 256 + tid;
        int row = rbase + (f >> 5);
        float4 v = make_float4(0.f, 0.f, 0.f, 0.f);
        if (row < n) v = *(const float4*)(X + (size_t)row * 128 + (f & 31) * 4);
        *(float4*)&As[f >> 5][(f & 31) * 4] = v;
    }

    for (int p = 0; p < 8; ++p) {
        const int kb = p * 16;
        if (p) __syncthreads();
        *(float4*)&Ws[tid >> 5][(tid & 31) * 4] = wreg0;
        *(float4*)&Ws[(tid >> 5) + 8][(tid & 31) * 4] = wreg1;
        if (p < 7) {
            const float* wp = W + (size_t)(kb + 16) * 128;
            wreg0 = *(const float4*)(wp + (size_t)tid * 4);
            wreg1 = *(const float4*)(wp + (size_t)(tid + 256) * 4);
        }
        __syncthreads();
#pragma unroll
        for (int kq = 0; kq < 4; ++kq) {
            int k = kq * 4;
            float4 w0 = *(float4*)&Ws[k + 0][cc * 4];
            float4 w1 = *(float4*)&Ws[k + 1][cc * 4];
            float4 w2 = *(float4*)&Ws[k + 2][cc * 4];
            float4 w3 = *(float4*)&Ws[k + 3][cc * 4];
#pragma unroll
            for (int i = 0; i < 4; ++i) {
                float4 a = *(float4*)&As[r0 + i][kb + k];
                acc[i][0] += a.x * w0.x + a.y * w1.x + a.z * w2.x + a.w * w3.x;
                acc[i][1] += a.x * w0.y + a.y * w1.y + a.z * w2.y + a.w * w3.y;
                acc[i][2] += a.x * w0.z + a.y * w1.z + a.z * w2.z + a.w * w3.z;
                acc[i][3] += a.x * w0.w + a.y * w1.w + a.z * w2.w + a.w * w3.w;
            }
        }
    }
    float4 b4 = *(const float4*)(bias + cc * 4);
#pragma unroll
    for (int i = 0; i < 4; ++i) {
        int gr = rbase + r0 + i;
        if (gr < n) {
            float4 o = make_float4(fmaxf(acc[i][0] + b4.x, 0.f), fmaxf(acc[i][1] + b4.y, 0.f),
                                   fmaxf(acc[i][2] + b4.z, 0.f), fmaxf(acc[i][3] + b4.w, 0.f));
            *(float4*)(out + (size_t)gr * 128 + cc * 4) = o;
        }
    }
}

// ================= gemm_maxk body (32-row tile; select lane-layout unchanged) =================
static __device__ __forceinline__ void gemm_maxk_body(float (*As)[128], float (*Ws)[128],
                                                      const float* __restrict__ A,
                                                      const float* __restrict__ W,
                                                      const float* __restrict__ bias,
                                                      const int* __restrict__ scnt,
                                                      float* __restrict__ svals,
                                                      int n, int rbase) {
    const int tid = threadIdx.x;
    const int cc = tid & 31;
    const int r0 = (tid >> 5) * 4;
    float acc[4][4];
#pragma unroll
    for (int i = 0; i < 4; ++i) { acc[i][0] = 0.f; acc[i][1] = 0.f; acc[i][2] = 0.f; acc[i][3] = 0.f; }

    float4 wreg0 = *(const float4*)(W + (size_t)tid * 4);
    float4 wreg1 = *(const float4*)(W + (size_t)(tid + 256) * 4);

    // stage A (hbuf padded; 100000 = 3125*32 exact)
#pragma unroll
    for (int q = 0; q < 4; ++q) {
        int f = q * 256 + tid;
        *(float4*)&As[f >> 5][(f & 31) * 4] =
            *(const float4*)(A + (size_t)rbase * 128 + (size_t)f * 4);
    }

    for (int p = 0; p < 8; ++p) {
        const int kb = p * 16;
        if (p) __syncthreads();
        *(float4*)&Ws[tid >> 5][(tid & 31) * 4] = wreg0;
        *(float4*)&Ws[(tid >> 5) + 8][(tid & 31) * 4] = wreg1;
        if (p < 7) {
            const float* wp = W + (size_t)(kb + 16) * 128;
            wreg0 = *(const float4*)(wp + (size_t)tid * 4);
            wreg1 = *(const float4*)(wp + (size_t)(tid + 256) * 4);
        }
        __syncthreads();
#pragma unroll
        for (int kq = 0; kq < 4; ++kq) {
            int k = kq * 4;
            float4 w0 = *(float4*)&Ws[k + 0][cc * 4];
            float4 w1 = *(float4*)&Ws[k + 1][cc * 4];
            float4 w2 = *(float4*)&Ws[k + 2][cc * 4];
            float4 w3 = *(float4*)&Ws[k + 3][cc * 4];
#pragma unroll
            for (int i = 0; i < 4; ++i) {
                float4 a = *(float4*)&As[r0 + i][kb + k];
                acc[i][0] += a.x * w0.x + a.y * w1.x + a.z * w2.x + a.w * w3.x;
                acc[i][1] += a.x * w0.y + a.y * w1.y + a.z * w2.y + a.w * w3.y;
                acc[i][2] += a.x * w0.z + a.y * w1.z + a.z * w2.z + a.w * w3.z;
                acc[i][3] += a.x * w0.w + a.y * w1.w + a.z * w2.w + a.w * w3.w;
            }
        }
    }

    // ---- fused MaxK select (verified logic; 4 rows/thread) ----
    const int lane = tid & 63;
    const int wvi = tid >> 6;
    const bool up = lane >= 32;
    const unsigned lt32 = (1u << (lane & 31)) - 1u;
    float4 b4 = *(const float4*)(bias + cc * 4);

    unsigned keys[4][4];
#pragma unroll
    for (int i = 0; i < 4; ++i) {
        acc[i][0] += b4.x; acc[i][1] += b4.y; acc[i][2] += b4.z; acc[i][3] += b4.w;
        keys[i][0] = sortable_key(acc[i][0]);
        keys[i][1] = sortable_key(acc[i][1]);
        keys[i][2] = sortable_key(acc[i][2]);
        keys[i][3] = sortable_key(acc[i][3]);
    }
    unsigned prefL[4], prefU[4];
#pragma unroll
    for (int i = 0; i < 4; ++i) { prefL[i] = 0u; prefU[i] = 0u; }

    for (int bit = 31; bit >= 8; --bit) {
        unsigned msk = 1u << bit;
#pragma unroll
        for (int i = 0; i < 4; ++i) {
            unsigned cL = prefL[i] | msk;
            unsigned cU = prefU[i] | msk;
            unsigned myc = up ? cU : cL;
            unsigned long long b0 = __ballot(keys[i][0] >= myc);
            unsigned long long b1 = __ballot(keys[i][1] >= myc);
            unsigned long long b2 = __ballot(keys[i][2] >= myc);
            unsigned long long b3 = __ballot(keys[i][3] >= myc);
            int cntL = __popc((unsigned)b0) + __popc((unsigned)b1) +
                       __popc((unsigned)b2) + __popc((unsigned)b3);
            int cntU = __popc((unsigned)(b0 >> 32)) + __popc((unsigned)(b1 >> 32)) +
                       __popc((unsigned)(b2 >> 32)) + __popc((unsigned)(b3 >> 32));
            prefL[i] = (cntL >= KSEL) ? cL : prefL[i];
            prefU[i] = (cntU >= KSEL) ? cU : prefU[i];
        }
    }

#pragma unroll 1
    for (int i = 0; i < 4; ++i) {
        int row = rbase + 8 * wvi + i + (up ? 4 : 0);
        unsigned myp = up ? prefU[i] : prefL[i];
        unsigned kb0 = keys[i][0] & 0xFFFFFF00u, kb1 = keys[i][1] & 0xFFFFFF00u;
        unsigned kb2 = keys[i][2] & 0xFFFFFF00u, kb3 = keys[i][3] & 0xFFFFFF00u;
        unsigned long long g0 = __ballot(kb0 > myp), g1 = __ballot(kb1 > myp);
        unsigned long long g2 = __ballot(kb2 > myp), g3 = __ballot(kb3 > myp);
        unsigned long long e0 = __ballot(kb0 == myp), e1 = __ballot(kb1 == myp);
        unsigned long long e2 = __ballot(kb2 == myp), e3 = __ballot(kb3 == myp);
        unsigned gh0 = up ? (unsigned)(g0 >> 32) : (unsigned)g0;
        unsigned gh1 = up ? (unsigned)(g1 >> 32) : (unsigned)g1;
        unsigned gh2 = up ? (unsigned)(g2 >> 32) : (unsigned)g2;
        unsigned gh3 = up ? (unsigned)(g3 >> 32) : (unsigned)g3;
        unsigned eh0 = up ? (unsigned)(e0 >> 32) : (unsigned)e0;
        unsigned eh1 = up ? (unsigned)(e1 >> 32) : (unsigned)e1;
        unsigned eh2 = up ? (unsigned)(e2 >> 32) : (unsigned)e2;
        unsigned eh3 = up ? (unsigned)(e3 >> 32) : (unsigned)e3;
        int m = __popc(gh0) + __popc(gh1) + __popc(gh2) + __popc(gh3);
        int need = KSEL - m;
        int gpos = __popc(gh0 & lt32) + __popc(gh1 & lt32) + __popc(gh2 & lt32) + __popc(gh3 & lt32);
        int epos = __popc(eh0 & lt32) + __popc(eh1 & lt32) + __popc(eh2 & lt32) + __popc(eh3 & lt32);
        bool ok = row < n;
        float ds = 0.f;
        if (ok) ds = rsqrtf((float)max(scnt[row], 1));
        size_t base = (size_t)row * 32;
        unsigned cbit = (unsigned)(lane & 31);
        // j = 0
        {
            int slot = -1;
            if (kb0 > myp) slot = gpos;
            else if (kb0 == myp && epos < need) slot = m + epos;
            if (slot >= 0 && ok) {
                unsigned u = (__float_as_uint(acc[i][0] * ds) & 0xFFFFFF80u) | (unsigned)(cc * 4 + 0);
                svals[base + slot] = __uint_as_float(u);
            }
            gpos += (gh0 >> cbit) & 1u;
            epos += (eh0 >> cbit) & 1u;
        }
        // j = 1
        {
            int slot = -1;
            if (kb1 > myp) slot = gpos;
            else if (kb1 == myp && epos < need) slot = m + epos;
            if (slot >= 0 && ok) {
                unsigned u = (__float_as_uint(acc[i][1] * ds) & 0xFFFFFF80u) | (unsigned)(cc * 4 + 1);
                svals[base + slot] = __uint_as_float(u);
            }
            gpos += (gh1 >> cbit) & 1u;
            epos += (eh1 >> cbit) & 1u;
        }
        // j = 2
        {
            int slot = -1;
            if (kb2 > myp) slot = gpos;
            else if (kb2 == myp && epos < need) slot = m + epos;
            if (slot >= 0 && ok) {
                unsigned u = (__float_as_uint(acc[i][2] * ds) & 0xFFFFFF80u) | (unsigned)(cc * 4 + 2);
                svals[base + slot] = __uint_as_float(u);
            }
            gpos += (gh2 >> cbit) & 1u;
            epos += (eh2 >> cbit) & 1u;
        }
        // j = 3
        {
            int slot = -1;
            if (kb3 > myp) slot = gpos;
            else if (kb3 == myp && epos < need) slot = m + epos;
            if (slot >= 0 && ok) {
                unsigned u = (__float_as_uint(acc[i][3] * ds) & 0xFFFFFF80u) | (unsigned)(cc * 4 + 3);
                svals[base + slot] = __uint_as_float(u);
            }
        }
    }
}

// ================= fused K2: gemm_maxk#1 + csr_from_bin (hidden under it) =================
__global__ __launch_bounds__(256, 2) void fused_csr_maxk(const int* __restrict__ bin,
                                                         const int* __restrict__ bcnt,
                                                         int* __restrict__ row_off,
                                                         int* __restrict__ cnt_in,
                                                         float* __restrict__ dvin,
                                                         int* __restrict__ csr,
                                                         const float* __restrict__ A,
                                                         const float* __restrict__ W,
                                                         const float* __restrict__ bias,
                                                         const int* __restrict__ scnt,
                                                         float* __restrict__ svals) {
    __shared__ float As[32][128];
    __shared__ float Ws[16][128];
    const int tid = threadIdx.x;

    if (blockIdx.x >= GT) {
        // ---- csr branch: per-bucket node counts, offsets, scatter ----
        int* cnt8 = (int*)&As[0][0];
        int* cur8 = cnt8 + (1 << BSH);
        const int b = blockIdx.x - GT;
        if (tid < (1 << BSH)) cnt8[tid] = 0;
        __syncthreads();
        const int m = min(bcnt[b], CAP);
        const int base = b << CAPSH;
        for (int e = tid; e < m; e += 256) {
            atomicAdd(&cnt8[bin[base + e] & ((1 << BSH) - 1)], 1);
        }
        __syncthreads();
        if (tid < (1 << BSH)) {
            int pre = 0;
#pragma unroll
            for (int q = 0; q < (1 << BSH); ++q) pre += (q < tid) ? cnt8[q] : 0;
            int node = (b << BSH) + tid;
            int start = base + pre;
            if (node < NN) {
                row_off[node] = start;
                cnt_in[node] = cnt8[tid];
                dvin[node] = rsqrtf((float)max(cnt8[tid], 1));
            }
            cur8[tid] = start;
        }
        __syncthreads();
        for (int e = tid; e < m; e += 256) {
            int r = bin[base + e];
            int pos = atomicAdd(&cur8[r & ((1 << BSH) - 1)], 1);
            csr[pos] = r >> BSH;
        }
        return;
    }

    gemm_maxk_body(As, Ws, A, W, bias, scnt, svals, NN, blockIdx.x * 32);
}

// ================= standalone gemm_maxk (layer 2) =================
__global__ __launch_bounds__(256, 2) void gemm_maxk(const float* __restrict__ A,
                                                    const float* __restrict__ W,
                                                    const float* __restrict__ bias,
                                                    const int* __restrict__ scnt,
                                                    float* __restrict__ svals, int n) {
    __shared__ float As[32][128];
    __shared__ float Ws[16][128];
    gemm_maxk_body(As, Ws, A, W, bias, scnt, svals, n, blockIdx.x * 32);
}

// ---------------- CSR aggregation: atomic-free ----------------
// v12: 4 concurrent edge-gathers per sub (8 loads in flight per wave).
// R11 showed agg is latency-bound and TLP/MLP-hungry; standalone (high
// occupancy, 4KB LDS) is the right home for it -- deepen MLP, keep structure.
__global__ __launch_bounds__(256) void agg_kernel(const float* __restrict__ svals,
                                                  const int* __restrict__ row_off,
                                                  const int* __restrict__ cnt_in,
                                                  const int* __restrict__ csr_src,
                                                  const float* __restrict__ dvin,
                                                  const float* __restrict__ bg,
                                                  float* __restrict__ out, int n) {
    __shared__ float acc[4][2][128];  // [wave][slot][feature], wave-private
    const int wv = threadIdx.x >> 6;
    const int lane = threadIdx.x & 63;
    const int sub = lane >> 5;   // which edge slot
    const int j = lane & 31;     // entry within record
    const int node = blockIdx.x * 4 + wv;
    float* base0 = &acc[wv][0][0];
    base0[lane] = 0.f;
    base0[lane + 64] = 0.f;
    base0[lane + 128] = 0.f;
    base0[lane + 192] = 0.f;
    if (node < n) {
        int s0 = row_off[node], s1 = s0 + cnt_in[node];
        float* Ac = &acc[wv][sub][0];
        int e = s0 + sub;
        for (; e + 6 < s1; e += 8) {
            int sA = csr_src[e];
            int sB = csr_src[e + 2];
            int sC = csr_src[e + 4];
            int sD = csr_src[e + 6];
            float vA = svals[(size_t)sA * 32 + j];
            float vB = svals[(size_t)sB * 32 + j];
            float vC = svals[(size_t)sC * 32 + j];
            float vD = svals[(size_t)sD * 32 + j];
            Ac[(int)(__float_as_uint(vA) & 127u)] += vA;
            Ac[(int)(__float_as_uint(vB) & 127u)] += vB;
            Ac[(int)(__float_as_uint(vC) & 127u)] += vC;
            Ac[(int)(__float_as_uint(vD) & 127u)] += vD;
        }
        for (; e < s1; e += 2) {
            int sA = csr_src[e];
            float vA = svals[(size_t)sA * 32 + j];
            Ac[(int)(__float_as_uint(vA) & 127u)] += vA;
        }
    }
    if (node < n) {
        float dv = dvin[node];
        float r0 = acc[wv][0][lane] + acc[wv][1][lane];
        float r1 = acc[wv][0][lane + 64] + acc[wv][1][lane + 64];
        out[(size_t)node * 128 + lane] = r0 * dv + bg[lane];
        out[(size_t)node * 128 + lane + 64] = r1 * dv + bg[lane + 64];
    }
}

// ---------------- GEMM [n,128] x [128,64] + bias -> d_out ----------------
// v4 64-row body (verified R3-R10; R9 lesson: do not retile this one).
__global__ __launch_bounds__(256, 2) void gemm_out64(const float* __restrict__ A,
                                                     const float* __restrict__ W,
                                                     const float* __restrict__ bias,
                                                     float* __restrict__ out, int n) {
    __shared__ float As[64][128];   // 32KB
    __shared__ float Ws[32][64];    // 8KB
    const int tid = threadIdx.x;
    const int rbase = blockIdx.x * 64;
    const int cc = tid & 15;
    const int r0 = (tid >> 4) * 4;
    float acc[4][4];
#pragma unroll
    for (int i = 0; i < 4; ++i) { acc[i][0] = 0.f; acc[i][1] = 0.f; acc[i][2] = 0.f; acc[i][3] = 0.f; }

    float4 wreg0 = *(const float4*)(W + (size_t)tid * 4);
    float4 wreg1 = *(const float4*)(W + (size_t)(tid + 256) * 4);

#pragma unroll
    for (int q = 0; q < 8; ++q) {
        int f = q * 256 + tid;
        *(float4*)&As[f >> 5][(f & 31) * 4] =
            *(const float4*)(A + (size_t)rbase * 128 + (size_t)f * 4);   // hbuf padded
    }

    for (int p = 0; p < 4; ++p) {
        const int kb = p * 32;
        if (p) __syncthreads();
        *(float4*)&Ws[tid >> 4][(tid & 15) * 4] = wreg0;
        *(float4*)&Ws[(tid >> 4) + 16][(tid & 15) * 4] = wreg1;
        if (p < 3) {
            const float* wp = W + (size_t)(kb + 32) * 64;
            wreg0 = *(const float4*)(wp + (size_t)tid * 4);
            wreg1 = *(const float4*)(wp + (size_t)(tid + 256) * 4);
        }
        __syncthreads();
#pragma unroll
        for (int kq = 0; kq < 8; ++kq) {
            int k = kq * 4;
            float4 w0 = *(float4*)&Ws[k + 0][cc * 4];
            float4 w1 = *(float4*)&Ws[k + 1][cc * 4];
            float4 w2 = *(float4*)&Ws[k + 2][cc * 4];
            float4 w3 = *(float4*)&Ws[k + 3][cc * 4];
#pragma unroll
            for (int i = 0; i < 4; ++i) {
                float4 a = *(float4*)&As[r0 + i][kb + k];
                acc[i][0] += a.x * w0.x + a.y * w1.x + a.z * w2.x + a.w * w3.x;
                acc[i][1] += a.x * w0.y + a.y * w1.y + a.z * w2.y + a.w * w3.y;
                acc[i][2] += a.x * w0.z + a.y * w1.z + a.z * w2.z + a.w * w3.z;
                acc[i][3] += a.x * w0.w + a.y * w1.w + a.z * w2.w + a.w * w3.w;
            }
        }
    }
    float4 b4 = *(const float4*)(bias + cc * 4);
#pragma unroll
    for (int i = 0; i < 4; ++i) {
        int gr = rbase + r0 + i;
        if (gr < n) {
            float4 o = make_float4(acc[i][0] + b4.x, acc[i][1] + b4.y,
                                   acc[i][2] + b4.z, acc[i][3] + b4.w);
            *(float4*)(out + (size_t)gr * 64 + cc * 4) = o;
        }
    }
}

extern "C" void kernel_launch(void* const* d_in, const int* in_sizes, int n_in,
                              void* d_out, int out_size, void* d_ws, size_t ws_size,
                              hipStream_t stream) {
    const float* x     = (const float*)d_in[0];
    const int*   src   = (const int*)d_in[1];
    const int*   dst   = (const int*)d_in[2];
    const float* W_in  = (const float*)d_in[3];
    const float* b_in  = (const float*)d_in[4];
    const float* W1    = (const float*)d_in[5];
    const float* b1    = (const float*)d_in[6];
    const float* bg1   = (const float*)d_in[7];
    const float* W2    = (const float*)d_in[8];
    const float* b2    = (const float*)d_in[9];
    const float* bg2   = (const float*)d_in[10];
    const float* W_out = (const float*)d_in[11];
    const float* b_out = (const float*)d_in[12];
    float* out = (float*)d_out;

    char* p = (char*)d_ws;
    auto carve = [&](size_t bytes) {
        char* r = p;
        p += (bytes + 255) & ~(size_t)255;
        return r;
    };
    int*   scnt    = (int*)carve((size_t)NN * 4);
    int*   bcnt    = (int*)carve((size_t)NBK * 4);
    float* dvin    = (float*)carve((size_t)NN * 4);
    int*   row_off = (int*)carve((size_t)NN * 4);
    int*   cnt_in  = (int*)carve((size_t)NN * 4);
    int*   bin     = (int*)carve((size_t)NBK * CAP * 4);     // 12.8MB packed records
    int*   csr_src = (int*)carve((size_t)NBK * CAP * 4);     // 12.8MB fixed-stride
    float* hbuf    = (float*)carve((size_t)(NN + 128) * HIDF * 4);  // padded rows
    float* svals   = (float*)carve((size_t)NN * KSEL * 4);

    const int gAgg = (NN + 3) / 4;       // 25000

    hipMemsetAsync(scnt, 0, (size_t)NN * 4, stream);
    hipMemsetAsync(bcnt, 0, (size_t)NBK * 4, stream);

    // K1: binning interleaved 2:1 with input GEMM (pattern of 3: bin,bin,gemm)
    fused_bin_relu<<<GT * 3, 256, 0, stream>>>(src, dst, bcnt, scnt, bin,
                                               x, W_in, b_in, hbuf);
    // K2: layer-1 GEMM+MaxK overlapped with CSR materialization
    fused_csr_maxk<<<GT + NBK, 256, 0, stream>>>(bin, bcnt, row_off, cnt_in, dvin, csr_src,
                                                 hbuf, W1, b1, scnt, svals);
    agg_kernel<<<gAgg, 256, 0, stream>>>(svals, row_off, cnt_in, csr_src, dvin, bg1, hbuf, NN);

    gemm_maxk<<<GT, 256, 0, stream>>>(hbuf, W2, b2, scnt, svals, NN);
    agg_kernel<<<gAgg, 256, 0, stream>>>(svals, row_off, cnt_in, csr_src, dvin, bg2, hbuf, NN);

    gemm_out64<<<GT64, 256, 0, stream>>>(hbuf, W_out, b_out, out, NN);
}